// Round 5
// baseline (10104.742 us; speedup 1.0000x reference)
//
#include <hip/hip_runtime.h>
#include <hip/hip_bf16.h>

// ---------------------------------------------------------------------------
// LSTM_66675072303478: 2-layer LSTM (B=512,S=128,E=7,H=1024) + FC(1024->672)
//
// v5 = v4 with the DUAL A-indexing bug fixed (v4 read h_a(t-1) instead of
// h_b(t-1) in layer-1's recurrent half: `arow1 + k0 - 1024` vs correct
// `arow1 + k0` where h_b occupies columns [1024,2048) of the ping buffer).
//
// Structure: persistent kernel, 256 blocks (1/CU), XCD-local groups:
//  - block reads HW_REG_XCC_ID, claims slot on its XCD; the 32 blocks of one
//    XCD form one batch-stripe group -> all h exchange stays in local L2.
//  - relaxed-only flag atomics (no L2 wb/inv), h loads via relaxed atomic
//    dwords (L1 bypass), weights plain cached loads (LLC-resident).
//  - K-loop: unroll x2, prefetch distance 2. LSTM cell fused in epilogue,
//    c-state in registers, gate-interleaved bf16 weights.
// ---------------------------------------------------------------------------

typedef __bf16 bf16x8 __attribute__((ext_vector_type(8)));
typedef float  f32x4  __attribute__((ext_vector_type(4)));

#define LDST 40   // LDS row stride in bf16 elems (32 data + 8 pad)

__device__ __forceinline__ float sigm_f(float x) {
    x = fminf(30.f, fmaxf(-30.f, x));
    return 1.0f / (1.0f + __expf(-x));
}
__device__ __forceinline__ float tanh_f(float x) {
    x = fminf(30.f, fmaxf(-30.f, x));
    float e = __expf(-2.0f * x);
    return (1.0f - e) / (1.0f + e);
}

// n' = (j/16)*64 + g*16 + (j%16)  ->  original gate-major row g*1024 + j
__device__ __forceinline__ int perm_row(int np) {
    int g = (np >> 4) & 3;
    int j = ((np >> 6) << 4) | (np & 15);
    return g * 1024 + j;
}

// ---- relaxed-only flag ops (NO acquire/release -> no L2 inv/wb) ------------
__device__ __forceinline__ void spin_ge(const int* p, int target) {
    while (__hip_atomic_load(p, __ATOMIC_RELAXED, __HIP_MEMORY_SCOPE_AGENT) < target)
        __builtin_amdgcn_s_sleep(1);
}
__device__ __forceinline__ void signal_inc(int* p) {
    __hip_atomic_fetch_add(p, 1, __ATOMIC_RELAXED, __HIP_MEMORY_SCOPE_AGENT);
}

// 16B h-load as 4 relaxed agent atomic dwords: bypasses (possibly stale) L1,
// served by the XCD-local TCC which holds the producers' stores.
__device__ __forceinline__ uint4 loadA16(const __bf16* p) {
    const unsigned* u = (const unsigned*)p;
    uint4 r;
    r.x = __hip_atomic_load(u + 0, __ATOMIC_RELAXED, __HIP_MEMORY_SCOPE_AGENT);
    r.y = __hip_atomic_load(u + 1, __ATOMIC_RELAXED, __HIP_MEMORY_SCOPE_AGENT);
    r.z = __hip_atomic_load(u + 2, __ATOMIC_RELAXED, __HIP_MEMORY_SCOPE_AGENT);
    r.w = __hip_atomic_load(u + 3, __ATOMIC_RELAXED, __HIP_MEMORY_SCOPE_AGENT);
    return r;
}

// ---------------- weight prep kernels (run every call) ----------------------

__global__ void prep_w0(const float* __restrict__ Wh0, __bf16* __restrict__ W0p) {
    int idx = blockIdx.x * 256 + threadIdx.x;
    int np = idx >> 8, k4 = (idx & 255) << 2;
    int r = perm_row(np);
    float4 v = *(const float4*)(Wh0 + r * 1024 + k4);
    __bf16* o = W0p + np * 1024 + k4;
    o[0] = (__bf16)v.x; o[1] = (__bf16)v.y; o[2] = (__bf16)v.z; o[3] = (__bf16)v.w;
}

__global__ void prep_w1(const float* __restrict__ Wi1, const float* __restrict__ Wh1,
                        __bf16* __restrict__ W1p) {
    int idx = blockIdx.x * 256 + threadIdx.x;
    int np = idx >> 9, k4 = (idx & 511) << 2;
    int r = perm_row(np);
    const float* s = (k4 < 1024) ? (Wi1 + r * 1024 + k4) : (Wh1 + r * 1024 + (k4 - 1024));
    float4 v = *(const float4*)s;
    __bf16* o = W1p + np * 2048 + k4;
    o[0] = (__bf16)v.x; o[1] = (__bf16)v.y; o[2] = (__bf16)v.z; o[3] = (__bf16)v.w;
}

__global__ void prep_wfc(const float* __restrict__ Wfc, __bf16* __restrict__ Wfcp) {
    int idx = blockIdx.x * 256 + threadIdx.x;
    int n = idx >> 8, k4 = (idx & 255) << 2;
    __bf16* o = Wfcp + n * 1024 + k4;
    if (n < 672) {
        float4 v = *(const float4*)(Wfc + n * 1024 + k4);
        o[0] = (__bf16)v.x; o[1] = (__bf16)v.y; o[2] = (__bf16)v.z; o[3] = (__bf16)v.w;
    } else {
        o[0] = (__bf16)0.f; o[1] = (__bf16)0.f; o[2] = (__bf16)0.f; o[3] = (__bf16)0.f;
    }
}

__global__ void prep_small(const float* __restrict__ Wi0, const float* __restrict__ b0,
                           const float* __restrict__ b1,
                           float* __restrict__ Wi0p, float* __restrict__ b1p) {
    int np = blockIdx.x * 256 + threadIdx.x;
    int r = perm_row(np);
    float* o = Wi0p + np * 8;
    #pragma unroll
    for (int q = 0; q < 7; ++q) o[q] = Wi0[r * 7 + q];
    o[7] = b0[r];
    b1p[np] = b1[r];
}

// ---------------- shared K-loop: unroll x2, prefetch depth 2 ---------------
// Tile 64x128, 256 thr = 4 waves 2x2, wave tile 32x64, BK=32.
// A rows stride 2048; DUAL: k<1024 from A0, k>=1024 from A1 (FULL k index:
// h_b data physically lives at columns [1024,2048) of A1's buffer).
// A loads use loadA16 (L1-bypass); B (weights) use plain cached dwordx4.

template <int KTOT, bool DUAL>
__device__ __forceinline__ void kloop(const __bf16* __restrict__ A0,
                                      const __bf16* __restrict__ A1,
                                      const __bf16* __restrict__ W,
                                      int n0, int m0, int tid,
                                      __bf16* Alds, __bf16* Blds,
                                      f32x4 (&acc)[2][4]) {
    const int a_r = tid >> 2;
    const int a_c = (tid & 3) << 3;
    const __bf16* wrow = W + (size_t)(n0 + a_r) * KTOT + a_c;
    const __bf16* arow0 = A0 + (m0 + a_r) * 2048 + a_c;
    const __bf16* arow1 = DUAL ? (A1 + (m0 + a_r) * 2048 + a_c) : arow0;

    const int l  = tid & 63, w = tid >> 6;
    const int wm = w & 1,   wn = w >> 1;
    const int lj = l & 15,  lq = l >> 4;

    #pragma unroll
    for (int i = 0; i < 2; ++i)
        #pragma unroll
        for (int j = 0; j < 4; ++j)
            acc[i][j] = (f32x4){0.f, 0.f, 0.f, 0.f};

    constexpr int NIT = KTOT / 32;

    // prefetch iters 0 and 1 (k0 = 0 and 32: both < 1024 -> arow0)
    uint4 ra0 = loadA16(arow0);
    uint4 rb00 = *(const uint4*)(wrow);
    uint4 rb10 = *(const uint4*)(wrow + (size_t)64 * KTOT);
    uint4 ra1 = loadA16(arow0 + 32);
    uint4 rb01 = *(const uint4*)(wrow + 32);
    uint4 rb11 = *(const uint4*)(wrow + (size_t)64 * KTOT + 32);

    const __bf16* Ap = Alds + (wm * 32 + lj) * LDST + lq * 8;
    const __bf16* Bp = Blds + (wn * 64 + lj) * LDST + lq * 8;

    for (int it = 0; it < NIT; it += 2) {
        // ---- even sub-iter: consume (ra0,rb*0), prefetch it+2 ----
        __syncthreads();
        *(uint4*)(Alds + a_r * LDST + a_c) = ra0;
        *(uint4*)(Blds + a_r * LDST + a_c) = rb00;
        *(uint4*)(Blds + (a_r + 64) * LDST + a_c) = rb10;
        __syncthreads();
        if (it + 2 < NIT) {
            int k0 = (it + 2) * 32;
            ra0 = loadA16(((!DUAL || k0 < 1024) ? arow0 : arow1) + k0);
            rb00 = *(const uint4*)(wrow + k0);
            rb10 = *(const uint4*)(wrow + (size_t)64 * KTOT + k0);
        }
        {
            bf16x8 af0 = *(const bf16x8*)(Ap);
            bf16x8 af1 = *(const bf16x8*)(Ap + 16 * LDST);
            #pragma unroll
            for (int ni = 0; ni < 4; ++ni) {
                bf16x8 bfr = *(const bf16x8*)(Bp + ni * 16 * LDST);
                acc[0][ni] = __builtin_amdgcn_mfma_f32_16x16x32_bf16(af0, bfr, acc[0][ni], 0, 0, 0);
                acc[1][ni] = __builtin_amdgcn_mfma_f32_16x16x32_bf16(af1, bfr, acc[1][ni], 0, 0, 0);
            }
        }
        // ---- odd sub-iter: consume (ra1,rb*1), prefetch it+3 ----
        __syncthreads();
        *(uint4*)(Alds + a_r * LDST + a_c) = ra1;
        *(uint4*)(Blds + a_r * LDST + a_c) = rb01;
        *(uint4*)(Blds + (a_r + 64) * LDST + a_c) = rb11;
        __syncthreads();
        if (it + 3 < NIT) {
            int k0 = (it + 3) * 32;
            ra1 = loadA16(((!DUAL || k0 < 1024) ? arow0 : arow1) + k0);
            rb01 = *(const uint4*)(wrow + k0);
            rb11 = *(const uint4*)(wrow + (size_t)64 * KTOT + k0);
        }
        {
            bf16x8 af0 = *(const bf16x8*)(Ap);
            bf16x8 af1 = *(const bf16x8*)(Ap + 16 * LDST);
            #pragma unroll
            for (int ni = 0; ni < 4; ++ni) {
                bf16x8 bfr = *(const bf16x8*)(Bp + ni * 16 * LDST);
                acc[0][ni] = __builtin_amdgcn_mfma_f32_16x16x32_bf16(af0, bfr, acc[0][ni], 0, 0, 0);
                acc[1][ni] = __builtin_amdgcn_mfma_f32_16x16x32_bf16(af1, bfr, acc[1][ni], 0, 0, 0);
            }
        }
    }
}

// ---------------- persistent LSTM kernel ------------------------------------
// 256 blocks, 1/CU. Block role: mb = XCD id (8 groups of 64 batch rows),
// nb = claimed slot on that XCD (32 gate-column blocks). All producer/consumer
// traffic for a group stays inside one XCD's L2.
// Flags (256B apart): F[mb]=cntA epochs, F[8+mb]=cntB epochs.

__global__ __launch_bounds__(256)
void lstm_persist(const float* __restrict__ x,
                  const __bf16* __restrict__ W0p, const __bf16* __restrict__ W1p,
                  const __bf16* __restrict__ Wfcp,
                  const float* __restrict__ Wi0p, const float* __restrict__ b1p,
                  const float* __restrict__ bfc,
                  __bf16* __restrict__ Ab0, __bf16* __restrict__ Ab1,
                  char* __restrict__ cntpage, float* __restrict__ out) {
    __shared__ __attribute__((aligned(16))) __bf16 Alds[64 * LDST];
    __shared__ __attribute__((aligned(16))) __bf16 Blds[128 * LDST];
    __shared__ float Aux1[128];
    __shared__ float Xlds[64 * 9];
    __shared__ float Wxlds[128 * 9];
    __shared__ int role[2];

    const int tid = threadIdx.x;

    // ---- claim XCD-local role ----
    if (tid == 0) {
        int xcd = __builtin_amdgcn_s_getreg(63508) & 7;   // HW_REG_XCC_ID (id 20, w32)
        int* xcnt = (int*)(cntpage + 4096) + xcd;
        int slot = __hip_atomic_fetch_add(xcnt, 1, __ATOMIC_RELAXED,
                                          __HIP_MEMORY_SCOPE_AGENT);
        role[0] = xcd; role[1] = slot;
    }
    __syncthreads();
    const int mb = role[0], nb = role[1];
    const int n0 = nb * 128, m0 = mb * 64;
    int* cA = (int*)(cntpage + (size_t)mb * 256);
    int* cB = (int*)(cntpage + (size_t)(8 + mb) * 256);

    // one-time per-block epilogue constants
    if (tid < 128) {
        Aux1[tid] = b1p[n0 + tid];
    } else {
        int nl = tid - 128;
        const float* s = Wi0p + (n0 + nl) * 8;
        float* d = Wxlds + nl * 9;
        #pragma unroll
        for (int q = 0; q < 8; ++q) d[q] = s[q];
    }

    const int l  = tid & 63, w = tid >> 6;
    const int wm = w & 1,   wn = w >> 1;
    const int lj = l & 15,  lq = l >> 4;
    const int jc = (n0 >> 2) + wn * 16 + lj;   // this thread's hidden column

    float c0[2][4], c1[2][4];
    #pragma unroll
    for (int i = 0; i < 2; ++i)
        #pragma unroll
        for (int r = 0; r < 4; ++r) { c0[i][r] = 0.f; c1[i][r] = 0.f; }

    f32x4 acc[2][4];

    for (int t = 0; t < 128; ++t) {
        __bf16* hprev = (t & 1) ? Ab1 : Ab0;   // h(t-1); h(-1)=zeros in Ab0
        __bf16* hcur  = (t & 1) ? Ab0 : Ab1;

        // stage x_t (read-only input, no dependency)
        if (tid < 64) {
            const float* xr = x + (m0 + tid) * 896 + t * 7;
            float* d = Xlds + tid * 9;
            #pragma unroll
            for (int q = 0; q < 7; ++q) d[q] = xr[q];
            d[7] = 1.0f;
        }

        // ---- phase 0: gates_a = h_a(t-1) @ Wh0^T (+ x_t dot in epilogue) ---
        if (tid == 0) spin_ge(cA, 32 * t);
        __syncthreads();
        kloop<1024, false>(hprev, nullptr, W0p, n0, m0, tid, Alds, Blds, acc);

        #pragma unroll
        for (int mi = 0; mi < 2; ++mi) {
            #pragma unroll
            for (int r = 0; r < 4; ++r) {
                int ml = wm * 32 + mi * 16 + lq * 4 + r;
                int m  = m0 + ml;
                float pre[4];
                #pragma unroll
                for (int g = 0; g < 4; ++g) pre[g] = acc[mi][g][r];
                const float* xr = Xlds + ml * 9;
                #pragma unroll
                for (int g = 0; g < 4; ++g) {
                    const float* wx = Wxlds + (wn * 64 + g * 16 + lj) * 9;
                    float s = 0.f;
                    #pragma unroll
                    for (int q = 0; q < 8; ++q) s += xr[q] * wx[q];
                    pre[g] += s;
                }
                float ig = sigm_f(pre[0]);
                float fg = sigm_f(pre[1]);
                float gv = tanh_f(pre[2]);
                float og = sigm_f(pre[3]);
                float cn = fg * c0[mi][r] + ig * gv;
                c0[mi][r] = cn;
                hcur[m * 2048 + jc] = (__bf16)(og * tanh_f(cn));
            }
        }
        __syncthreads();                 // barrier implies per-wave vmcnt(0) drain
        if (tid == 0) signal_inc(cA);

        // ---- phase 1: gates_b = [h_a(t) | h_b(t-1)] @ [Wi1|Wh1]^T + b1 -----
        if (tid == 0) { spin_ge(cA, 32 * (t + 1)); spin_ge(cB, 32 * t); }
        __syncthreads();
        kloop<2048, true>(hcur, hprev, W1p, n0, m0, tid, Alds, Blds, acc);

        #pragma unroll
        for (int mi = 0; mi < 2; ++mi) {
            #pragma unroll
            for (int r = 0; r < 4; ++r) {
                int m = m0 + wm * 32 + mi * 16 + lq * 4 + r;
                float pre[4];
                #pragma unroll
                for (int g = 0; g < 4; ++g)
                    pre[g] = acc[mi][g][r] + Aux1[wn * 64 + g * 16 + lj];
                float ig = sigm_f(pre[0]);
                float fg = sigm_f(pre[1]);
                float gv = tanh_f(pre[2]);
                float og = sigm_f(pre[3]);
                float cn = fg * c1[mi][r] + ig * gv;
                c1[mi][r] = cn;
                hcur[m * 2048 + 1024 + jc] = (__bf16)(og * tanh_f(cn));
            }
        }
        __syncthreads();
        if (tid == 0) signal_inc(cB);
    }

    // ---- final FC: pred = h_b(127) @ Wfc^T + bfc  (slots 0..5 only) --------
    if (nb < 6) {
        if (tid == 0) spin_ge(cB, 32 * 128);
        __syncthreads();
        if (tid < 128) {
            int n = n0 + tid;
            Aux1[tid] = (n < 672) ? bfc[n] : 0.f;
        }
        __syncthreads();
        // h_b(127) is in Ab0 (t=127 odd -> hcur=Ab0), cols 1024..2047
        kloop<1024, false>(Ab0 + 1024, nullptr, Wfcp, n0, m0, tid, Alds, Blds, acc);
        #pragma unroll
        for (int mi = 0; mi < 2; ++mi) {
            #pragma unroll
            for (int r = 0; r < 4; ++r) {
                int m = m0 + wm * 32 + mi * 16 + lq * 4 + r;
                #pragma unroll
                for (int ni = 0; ni < 4; ++ni) {
                    int n = n0 + wn * 64 + ni * 16 + lj;
                    if (n < 672)
                        out[m * 672 + n] = acc[mi][ni][r] + Aux1[wn * 64 + ni * 16 + lj];
                }
            }
        }
    }
}

// ---------------- workspace layout (bytes) ----------------------------------
#define O_W0P   0u            // 4096*1024*2  = 8388608
#define O_W1P   8388608u      // 4096*2048*2  = 16777216
#define O_WFCP  25165824u     // 768*1024*2   = 1572864
#define O_WI0P  26738688u     // 4096*8*4     = 131072
#define O_B1P   26869760u     // 4096*4       = 16384
#define O_AB0   26886144u     // 512*2048*2   = 2097152   (zeroed: h(-1)=0)
#define O_CNT   28983296u     // 8192: 16 flags @256B + xcdCnt[8] @ +4096 (zeroed)
#define O_AB1   28991488u     // 512*2048*2   = 2097152
#define WS_NEED 31088640u

extern "C" void kernel_launch(void* const* d_in, const int* in_sizes, int n_in,
                              void* d_out, int out_size, void* d_ws, size_t ws_size,
                              hipStream_t stream) {
    const float* x   = (const float*)d_in[0];
    const float* Wi0 = (const float*)d_in[1];
    const float* Wh0 = (const float*)d_in[2];
    const float* b0  = (const float*)d_in[3];
    const float* Wi1 = (const float*)d_in[4];
    const float* Wh1 = (const float*)d_in[5];
    const float* b1  = (const float*)d_in[6];
    const float* Wfc = (const float*)d_in[7];
    const float* bfc = (const float*)d_in[8];
    float* out = (float*)d_out;
    char*  ws  = (char*)d_ws;
    if (ws_size < WS_NEED) return;

    __bf16* W0p  = (__bf16*)(ws + O_W0P);
    __bf16* W1p  = (__bf16*)(ws + O_W1P);
    __bf16* Wfcp = (__bf16*)(ws + O_WFCP);
    float*  Wi0p = (float*)(ws + O_WI0P);
    float*  b1p  = (float*)(ws + O_B1P);
    __bf16* Ab0  = (__bf16*)(ws + O_AB0);
    char*   cnt  = (char*)(ws + O_CNT);
    __bf16* Ab1  = (__bf16*)(ws + O_AB1);

    // zero h(-1) buffer + flag page (contiguous region)
    hipMemsetAsync(ws + O_AB0, 0, 2097152u + 8192u, stream);

    prep_w0   <<<4096, 256, 0, stream>>>(Wh0, W0p);
    prep_w1   <<<8192, 256, 0, stream>>>(Wi1, Wh1, W1p);
    prep_wfc  <<<768,  256, 0, stream>>>(Wfc, Wfcp);
    prep_small<<<16,   256, 0, stream>>>(Wi0, b0, b1, Wi0p, b1p);

    lstm_persist<<<256, 256, 0, stream>>>(x, W0p, W1p, Wfcp, Wi0p, b1p, bfc,
                                          Ab0, Ab1, cnt, out);
}

// Round 6
// 6483.725 us; speedup vs baseline: 1.5585x; 1.5585x over previous
//
#include <hip/hip_runtime.h>
#include <hip/hip_bf16.h>

// ---------------------------------------------------------------------------
// LSTM_66675072303478: 2-layer LSTM (B=512,S=128,E=7,H=1024) + FC(1024->672)
//
// v6: v5 skeleton (persistent, XCD-local groups, relaxed flags) with the
// HBM-latency bug fixed:
//  - v5's agent atomic h-loads were serviced at HBM (FETCH 12.3 GB = exact
//    A-tile volume). v6 uses plain cached loads; L1 staleness is handled by
//    an L1-only `buffer_inv` after each flag wait (L2/MALL untouched, so
//    weights stay cached -- unlike v3's agent acquire which wiped L2).
//  - BK=64 per LDS stage: half the barriers, ~2x prefetch window (~600 cyc)
//    to cover L2/MALL latency for A and weight streams.
// ---------------------------------------------------------------------------

typedef __bf16 bf16x8 __attribute__((ext_vector_type(8)));
typedef float  f32x4  __attribute__((ext_vector_type(4)));

#define LDSTR 72   // LDS row stride in bf16 elems (64 data + 8 pad)

__device__ __forceinline__ float sigm_f(float x) {
    x = fminf(30.f, fmaxf(-30.f, x));
    return 1.0f / (1.0f + __expf(-x));
}
__device__ __forceinline__ float tanh_f(float x) {
    x = fminf(30.f, fmaxf(-30.f, x));
    float e = __expf(-2.0f * x);
    return (1.0f - e) / (1.0f + e);
}

// n' = (j/16)*64 + g*16 + (j%16)  ->  original gate-major row g*1024 + j
__device__ __forceinline__ int perm_row(int np) {
    int g = (np >> 4) & 3;
    int j = ((np >> 6) << 4) | (np & 15);
    return g * 1024 + j;
}

// ---- relaxed-only flag ops (NO acquire/release -> no L2 inv/wb) ------------
__device__ __forceinline__ void spin_ge(const int* p, int target) {
    while (__hip_atomic_load(p, __ATOMIC_RELAXED, __HIP_MEMORY_SCOPE_AGENT) < target)
        __builtin_amdgcn_s_sleep(1);
}
__device__ __forceinline__ void signal_inc(int* p) {
    __hip_atomic_fetch_add(p, 1, __ATOMIC_RELAXED, __HIP_MEMORY_SCOPE_AGENT);
}
// L1-only invalidate (sc bits = 0 -> CU scope). Leaves L2/MALL intact.
// Also acts as a compiler memory fence so h-loads can't be hoisted above it.
__device__ __forceinline__ void inv_l1() {
    asm volatile("buffer_inv" ::: "memory");
}

// ---------------- weight prep kernels (run every call) ----------------------

__global__ void prep_w0(const float* __restrict__ Wh0, __bf16* __restrict__ W0p) {
    int idx = blockIdx.x * 256 + threadIdx.x;
    int np = idx >> 8, k4 = (idx & 255) << 2;
    int r = perm_row(np);
    float4 v = *(const float4*)(Wh0 + r * 1024 + k4);
    __bf16* o = W0p + np * 1024 + k4;
    o[0] = (__bf16)v.x; o[1] = (__bf16)v.y; o[2] = (__bf16)v.z; o[3] = (__bf16)v.w;
}

__global__ void prep_w1(const float* __restrict__ Wi1, const float* __restrict__ Wh1,
                        __bf16* __restrict__ W1p) {
    int idx = blockIdx.x * 256 + threadIdx.x;
    int np = idx >> 9, k4 = (idx & 511) << 2;
    int r = perm_row(np);
    const float* s = (k4 < 1024) ? (Wi1 + r * 1024 + k4) : (Wh1 + r * 1024 + (k4 - 1024));
    float4 v = *(const float4*)s;
    __bf16* o = W1p + np * 2048 + k4;
    o[0] = (__bf16)v.x; o[1] = (__bf16)v.y; o[2] = (__bf16)v.z; o[3] = (__bf16)v.w;
}

__global__ void prep_wfc(const float* __restrict__ Wfc, __bf16* __restrict__ Wfcp) {
    int idx = blockIdx.x * 256 + threadIdx.x;
    int n = idx >> 8, k4 = (idx & 255) << 2;
    __bf16* o = Wfcp + n * 1024 + k4;
    if (n < 672) {
        float4 v = *(const float4*)(Wfc + n * 1024 + k4);
        o[0] = (__bf16)v.x; o[1] = (__bf16)v.y; o[2] = (__bf16)v.z; o[3] = (__bf16)v.w;
    } else {
        o[0] = (__bf16)0.f; o[1] = (__bf16)0.f; o[2] = (__bf16)0.f; o[3] = (__bf16)0.f;
    }
}

__global__ void prep_small(const float* __restrict__ Wi0, const float* __restrict__ b0,
                           const float* __restrict__ b1,
                           float* __restrict__ Wi0p, float* __restrict__ b1p) {
    int np = blockIdx.x * 256 + threadIdx.x;
    int r = perm_row(np);
    float* o = Wi0p + np * 8;
    #pragma unroll
    for (int q = 0; q < 7; ++q) o[q] = Wi0[r * 7 + q];
    o[7] = b0[r];
    b1p[np] = b1[r];
}

// ---------------- K-loop: BK=64 stages, prefetch 1 stage ahead --------------
// Tile 64x128, 256 thr = 4 waves 2x2, wave tile 32x64.
// A rows stride 2048; DUAL: k<1024 from A0, k>=1024 from A1 (FULL k index:
// h_b lives at columns [1024,2048) of A1's buffer). All loads plain cached.

template <int KTOT, bool DUAL>
__device__ __forceinline__ void kloop(const __bf16* __restrict__ A0,
                                      const __bf16* __restrict__ A1,
                                      const __bf16* __restrict__ W,
                                      int n0, int m0, int tid,
                                      __bf16* Alds, __bf16* Blds,
                                      f32x4 (&acc)[2][4]) {
    const int a_r = tid >> 2;             // 0..63
    const int a_c = (tid & 3) << 4;       // 0,16,32,48
    const int b_r = tid >> 1;             // 0..127
    const int b_c = (tid & 1) << 5;       // 0,32
    const __bf16* wrow  = W + (size_t)(n0 + b_r) * KTOT + b_c;
    const __bf16* arow0 = A0 + (m0 + a_r) * 2048 + a_c;
    const __bf16* arow1 = DUAL ? (A1 + (m0 + a_r) * 2048 + a_c) : arow0;

    const int l  = tid & 63, w = tid >> 6;
    const int wm = w & 1,   wn = w >> 1;
    const int lj = l & 15,  lq = l >> 4;

    #pragma unroll
    for (int i = 0; i < 2; ++i)
        #pragma unroll
        for (int j = 0; j < 4; ++j)
            acc[i][j] = (f32x4){0.f, 0.f, 0.f, 0.f};

    constexpr int NIT = KTOT / 64;

    uint4 ra0, ra1, rb0, rb1, rb2, rb3;
    auto lda = [&](int k0) {
        const __bf16* p = ((!DUAL || k0 < 1024) ? arow0 : arow1) + k0;
        ra0 = *(const uint4*)(p);
        ra1 = *(const uint4*)(p + 8);
    };
    auto ldb = [&](int k0) {
        const __bf16* p = wrow + k0;
        rb0 = *(const uint4*)(p);
        rb1 = *(const uint4*)(p + 8);
        rb2 = *(const uint4*)(p + 16);
        rb3 = *(const uint4*)(p + 24);
    };

    lda(0); ldb(0);

    const __bf16* Ap = Alds + (wm * 32 + lj) * LDSTR + lq * 8;
    const __bf16* Bp = Blds + (wn * 64 + lj) * LDSTR + lq * 8;

    for (int it = 0; it < NIT; ++it) {
        __syncthreads();
        *(uint4*)(Alds + a_r * LDSTR + a_c)      = ra0;
        *(uint4*)(Alds + a_r * LDSTR + a_c + 8)  = ra1;
        *(uint4*)(Blds + b_r * LDSTR + b_c)      = rb0;
        *(uint4*)(Blds + b_r * LDSTR + b_c + 8)  = rb1;
        *(uint4*)(Blds + b_r * LDSTR + b_c + 16) = rb2;
        *(uint4*)(Blds + b_r * LDSTR + b_c + 24) = rb3;
        __syncthreads();
        if (it + 1 < NIT) { int k0 = (it + 1) * 64; lda(k0); ldb(k0); }
        #pragma unroll
        for (int s = 0; s < 2; ++s) {
            bf16x8 af0 = *(const bf16x8*)(Ap + s * 32);
            bf16x8 af1 = *(const bf16x8*)(Ap + s * 32 + 16 * LDSTR);
            #pragma unroll
            for (int ni = 0; ni < 4; ++ni) {
                bf16x8 bfr = *(const bf16x8*)(Bp + s * 32 + ni * 16 * LDSTR);
                acc[0][ni] = __builtin_amdgcn_mfma_f32_16x16x32_bf16(af0, bfr, acc[0][ni], 0, 0, 0);
                acc[1][ni] = __builtin_amdgcn_mfma_f32_16x16x32_bf16(af1, bfr, acc[1][ni], 0, 0, 0);
            }
        }
    }
}

// ---------------- persistent LSTM kernel ------------------------------------
// 256 blocks, 1/CU. mb = XCD id (batch stripe of 64 rows), nb = claimed slot
// on that XCD (32 gate-column blocks). All h producer/consumer traffic for a
// group stays inside one XCD's L2. Flags: F[mb]=cntA, F[8+mb]=cntB.

__global__ __launch_bounds__(256)
void lstm_persist(const float* __restrict__ x,
                  const __bf16* __restrict__ W0p, const __bf16* __restrict__ W1p,
                  const __bf16* __restrict__ Wfcp,
                  const float* __restrict__ Wi0p, const float* __restrict__ b1p,
                  const float* __restrict__ bfc,
                  __bf16* __restrict__ Ab0, __bf16* __restrict__ Ab1,
                  char* __restrict__ cntpage, float* __restrict__ out) {
    __shared__ __attribute__((aligned(16))) __bf16 Alds[64 * LDSTR];
    __shared__ __attribute__((aligned(16))) __bf16 Blds[128 * LDSTR];
    __shared__ float Aux1[128];
    __shared__ float Xlds[64 * 9];
    __shared__ float Wxlds[128 * 9];
    __shared__ int role[2];

    const int tid = threadIdx.x;

    // ---- claim XCD-local role ----
    if (tid == 0) {
        int xcd = __builtin_amdgcn_s_getreg(63508) & 7;   // HW_REG_XCC_ID
        int* xcnt = (int*)(cntpage + 4096) + xcd;
        int slot = __hip_atomic_fetch_add(xcnt, 1, __ATOMIC_RELAXED,
                                          __HIP_MEMORY_SCOPE_AGENT);
        role[0] = xcd; role[1] = slot;
    }
    __syncthreads();
    const int mb = role[0], nb = role[1];
    const int n0 = nb * 128, m0 = mb * 64;
    int* cA = (int*)(cntpage + (size_t)mb * 256);
    int* cB = (int*)(cntpage + (size_t)(8 + mb) * 256);

    // one-time per-block epilogue constants
    if (tid < 128) {
        Aux1[tid] = b1p[n0 + tid];
    } else {
        int nl = tid - 128;
        const float* s = Wi0p + (n0 + nl) * 8;
        float* d = Wxlds + nl * 9;
        #pragma unroll
        for (int q = 0; q < 8; ++q) d[q] = s[q];
    }

    const int l  = tid & 63, w = tid >> 6;
    const int wm = w & 1,   wn = w >> 1;
    const int lj = l & 15,  lq = l >> 4;
    const int jc = (n0 >> 2) + wn * 16 + lj;   // this thread's hidden column

    float c0[2][4], c1[2][4];
    #pragma unroll
    for (int i = 0; i < 2; ++i)
        #pragma unroll
        for (int r = 0; r < 4; ++r) { c0[i][r] = 0.f; c1[i][r] = 0.f; }

    f32x4 acc[2][4];

    for (int t = 0; t < 128; ++t) {
        __bf16* hprev = (t & 1) ? Ab1 : Ab0;   // h(t-1); h(-1)=zeros in Ab0
        __bf16* hcur  = (t & 1) ? Ab0 : Ab1;

        // stage x_t (read-only input, no dependency)
        if (tid < 64) {
            const float* xr = x + (m0 + tid) * 896 + t * 7;
            float* d = Xlds + tid * 9;
            #pragma unroll
            for (int q = 0; q < 7; ++q) d[q] = xr[q];
            d[7] = 1.0f;
        }

        // ---- phase 0: gates_a = h_a(t-1) @ Wh0^T (+ x_t dot in epilogue) ---
        if (tid == 0) spin_ge(cA, 32 * t);
        __syncthreads();
        inv_l1();                              // drop stale h lines from L1
        kloop<1024, false>(hprev, nullptr, W0p, n0, m0, tid, Alds, Blds, acc);

        #pragma unroll
        for (int mi = 0; mi < 2; ++mi) {
            #pragma unroll
            for (int r = 0; r < 4; ++r) {
                int ml = wm * 32 + mi * 16 + lq * 4 + r;
                int m  = m0 + ml;
                float pre[4];
                #pragma unroll
                for (int g = 0; g < 4; ++g) pre[g] = acc[mi][g][r];
                const float* xr = Xlds + ml * 9;
                #pragma unroll
                for (int g = 0; g < 4; ++g) {
                    const float* wx = Wxlds + (wn * 64 + g * 16 + lj) * 9;
                    float s = 0.f;
                    #pragma unroll
                    for (int q = 0; q < 8; ++q) s += xr[q] * wx[q];
                    pre[g] += s;
                }
                float ig = sigm_f(pre[0]);
                float fg = sigm_f(pre[1]);
                float gv = tanh_f(pre[2]);
                float og = sigm_f(pre[3]);
                float cn = fg * c0[mi][r] + ig * gv;
                c0[mi][r] = cn;
                hcur[m * 2048 + jc] = (__bf16)(og * tanh_f(cn));
            }
        }
        __syncthreads();                 // barrier implies vmcnt(0) store drain
        if (tid == 0) signal_inc(cA);

        // ---- phase 1: gates_b = [h_a(t) | h_b(t-1)] @ [Wi1|Wh1]^T + b1 -----
        if (tid == 0) { spin_ge(cA, 32 * (t + 1)); spin_ge(cB, 32 * t); }
        __syncthreads();
        inv_l1();
        kloop<2048, true>(hcur, hprev, W1p, n0, m0, tid, Alds, Blds, acc);

        #pragma unroll
        for (int mi = 0; mi < 2; ++mi) {
            #pragma unroll
            for (int r = 0; r < 4; ++r) {
                int m = m0 + wm * 32 + mi * 16 + lq * 4 + r;
                float pre[4];
                #pragma unroll
                for (int g = 0; g < 4; ++g)
                    pre[g] = acc[mi][g][r] + Aux1[wn * 64 + g * 16 + lj];
                float ig = sigm_f(pre[0]);
                float fg = sigm_f(pre[1]);
                float gv = tanh_f(pre[2]);
                float og = sigm_f(pre[3]);
                float cn = fg * c1[mi][r] + ig * gv;
                c1[mi][r] = cn;
                hcur[m * 2048 + 1024 + jc] = (__bf16)(og * tanh_f(cn));
            }
        }
        __syncthreads();
        if (tid == 0) signal_inc(cB);
    }

    // ---- final FC: pred = h_b(127) @ Wfc^T + bfc  (slots 0..5 only) --------
    if (nb < 6) {
        if (tid == 0) spin_ge(cB, 32 * 128);
        __syncthreads();
        inv_l1();
        if (tid < 128) {
            int n = n0 + tid;
            Aux1[tid] = (n < 672) ? bfc[n] : 0.f;
        }
        __syncthreads();
        // h_b(127) is in Ab0 (t=127 odd -> hcur=Ab0), cols 1024..2047
        kloop<1024, false>(Ab0 + 1024, nullptr, Wfcp, n0, m0, tid, Alds, Blds, acc);
        #pragma unroll
        for (int mi = 0; mi < 2; ++mi) {
            #pragma unroll
            for (int r = 0; r < 4; ++r) {
                int m = m0 + wm * 32 + mi * 16 + lq * 4 + r;
                #pragma unroll
                for (int ni = 0; ni < 4; ++ni) {
                    int n = n0 + wn * 64 + ni * 16 + lj;
                    if (n < 672)
                        out[m * 672 + n] = acc[mi][ni][r] + Aux1[wn * 64 + ni * 16 + lj];
                }
            }
        }
    }
}

// ---------------- workspace layout (bytes) ----------------------------------
#define O_W0P   0u            // 4096*1024*2  = 8388608
#define O_W1P   8388608u      // 4096*2048*2  = 16777216
#define O_WFCP  25165824u     // 768*1024*2   = 1572864
#define O_WI0P  26738688u     // 4096*8*4     = 131072
#define O_B1P   26869760u     // 4096*4       = 16384
#define O_AB0   26886144u     // 512*2048*2   = 2097152   (zeroed: h(-1)=0)
#define O_CNT   28983296u     // 8192: 16 flags @256B + xcdCnt[8] @ +4096 (zeroed)
#define O_AB1   28991488u     // 512*2048*2   = 2097152
#define WS_NEED 31088640u

extern "C" void kernel_launch(void* const* d_in, const int* in_sizes, int n_in,
                              void* d_out, int out_size, void* d_ws, size_t ws_size,
                              hipStream_t stream) {
    const float* x   = (const float*)d_in[0];
    const float* Wi0 = (const float*)d_in[1];
    const float* Wh0 = (const float*)d_in[2];
    const float* b0  = (const float*)d_in[3];
    const float* Wi1 = (const float*)d_in[4];
    const float* Wh1 = (const float*)d_in[5];
    const float* b1  = (const float*)d_in[6];
    const float* Wfc = (const float*)d_in[7];
    const float* bfc = (const float*)d_in[8];
    float* out = (float*)d_out;
    char*  ws  = (char*)d_ws;
    if (ws_size < WS_NEED) return;

    __bf16* W0p  = (__bf16*)(ws + O_W0P);
    __bf16* W1p  = (__bf16*)(ws + O_W1P);
    __bf16* Wfcp = (__bf16*)(ws + O_WFCP);
    float*  Wi0p = (float*)(ws + O_WI0P);
    float*  b1p  = (float*)(ws + O_B1P);
    __bf16* Ab0  = (__bf16*)(ws + O_AB0);
    char*   cnt  = (char*)(ws + O_CNT);
    __bf16* Ab1  = (__bf16*)(ws + O_AB1);

    // zero h(-1) buffer + flag page (contiguous region)
    hipMemsetAsync(ws + O_AB0, 0, 2097152u + 8192u, stream);

    prep_w0   <<<4096, 256, 0, stream>>>(Wh0, W0p);
    prep_w1   <<<8192, 256, 0, stream>>>(Wi1, Wh1, W1p);
    prep_wfc  <<<768,  256, 0, stream>>>(Wfc, Wfcp);
    prep_small<<<16,   256, 0, stream>>>(Wi0, b0, b1, Wi0p, b1p);

    lstm_persist<<<256, 256, 0, stream>>>(x, W0p, W1p, Wfcp, Wi0p, b1p, bfc,
                                          Ab0, Ab1, cnt, out);
}

// Round 7
// 5159.497 us; speedup vs baseline: 1.9585x; 1.2567x over previous
//
#include <hip/hip_runtime.h>
#include <hip/hip_bf16.h>

// ---------------------------------------------------------------------------
// LSTM_66675072303478: 2-layer LSTM (B=512,S=128,E=7,H=1024) + FC(1024->672)
//
// v7: v6 + layer-pipelined dual workers.
//  - 512 blocks, 2/CU: each CU hosts one L0-worker (K=1024) and one
//    L1-worker (K=2048) running adjacent timesteps concurrently (wavefront
//    schedule). Doubles outstanding MALL requests (weight stream was
//    MLP-limited at 2 TB/s) and hides flag-spins/epilogues under the
//    partner's MFMA.
//  - Flags: cA[mb] += by L0 blocks, cB[mb] += by L1 blocks.
//    L0(t) waits cA>=32t && cB>=32(t-1); L1(t) waits cA>=32(t+1) && cB>=32t.
//  - Kloop/coherence model identical to v6 (XCD-local stripes, relaxed
//    flags, L1-only buffer_inv, BK=64, cached loads).
// ---------------------------------------------------------------------------

typedef __bf16 bf16x8 __attribute__((ext_vector_type(8)));
typedef float  f32x4  __attribute__((ext_vector_type(4)));

#define LDSTR 72   // LDS row stride in bf16 elems (64 data + 8 pad)

__device__ __forceinline__ float sigm_f(float x) {
    x = fminf(30.f, fmaxf(-30.f, x));
    return 1.0f / (1.0f + __expf(-x));
}
__device__ __forceinline__ float tanh_f(float x) {
    x = fminf(30.f, fmaxf(-30.f, x));
    float e = __expf(-2.0f * x);
    return (1.0f - e) / (1.0f + e);
}

// n' = (j/16)*64 + g*16 + (j%16)  ->  original gate-major row g*1024 + j
__device__ __forceinline__ int perm_row(int np) {
    int g = (np >> 4) & 3;
    int j = ((np >> 6) << 4) | (np & 15);
    return g * 1024 + j;
}

// ---- relaxed-only flag ops (NO acquire/release -> no L2 inv/wb) ------------
__device__ __forceinline__ void spin_ge(const int* p, int target) {
    while (__hip_atomic_load(p, __ATOMIC_RELAXED, __HIP_MEMORY_SCOPE_AGENT) < target)
        __builtin_amdgcn_s_sleep(1);
}
__device__ __forceinline__ void signal_inc(int* p) {
    __hip_atomic_fetch_add(p, 1, __ATOMIC_RELAXED, __HIP_MEMORY_SCOPE_AGENT);
}
// L1-only invalidate (sc bits = 0 -> CU scope). Leaves L2/MALL intact.
__device__ __forceinline__ void inv_l1() {
    asm volatile("buffer_inv" ::: "memory");
}

// ---------------- weight prep kernels (run every call) ----------------------

__global__ void prep_w0(const float* __restrict__ Wh0, __bf16* __restrict__ W0p) {
    int idx = blockIdx.x * 256 + threadIdx.x;
    int np = idx >> 8, k4 = (idx & 255) << 2;
    int r = perm_row(np);
    float4 v = *(const float4*)(Wh0 + r * 1024 + k4);
    __bf16* o = W0p + np * 1024 + k4;
    o[0] = (__bf16)v.x; o[1] = (__bf16)v.y; o[2] = (__bf16)v.z; o[3] = (__bf16)v.w;
}

__global__ void prep_w1(const float* __restrict__ Wi1, const float* __restrict__ Wh1,
                        __bf16* __restrict__ W1p) {
    int idx = blockIdx.x * 256 + threadIdx.x;
    int np = idx >> 9, k4 = (idx & 511) << 2;
    int r = perm_row(np);
    const float* s = (k4 < 1024) ? (Wi1 + r * 1024 + k4) : (Wh1 + r * 1024 + (k4 - 1024));
    float4 v = *(const float4*)s;
    __bf16* o = W1p + np * 2048 + k4;
    o[0] = (__bf16)v.x; o[1] = (__bf16)v.y; o[2] = (__bf16)v.z; o[3] = (__bf16)v.w;
}

__global__ void prep_wfc(const float* __restrict__ Wfc, __bf16* __restrict__ Wfcp) {
    int idx = blockIdx.x * 256 + threadIdx.x;
    int n = idx >> 8, k4 = (idx & 255) << 2;
    __bf16* o = Wfcp + n * 1024 + k4;
    if (n < 672) {
        float4 v = *(const float4*)(Wfc + n * 1024 + k4);
        o[0] = (__bf16)v.x; o[1] = (__bf16)v.y; o[2] = (__bf16)v.z; o[3] = (__bf16)v.w;
    } else {
        o[0] = (__bf16)0.f; o[1] = (__bf16)0.f; o[2] = (__bf16)0.f; o[3] = (__bf16)0.f;
    }
}

__global__ void prep_small(const float* __restrict__ Wi0, const float* __restrict__ b0,
                           const float* __restrict__ b1,
                           float* __restrict__ Wi0p, float* __restrict__ b1p) {
    int np = blockIdx.x * 256 + threadIdx.x;
    int r = perm_row(np);
    float* o = Wi0p + np * 8;
    #pragma unroll
    for (int q = 0; q < 7; ++q) o[q] = Wi0[r * 7 + q];
    o[7] = b0[r];
    b1p[np] = b1[r];
}

// ---------------- K-loop: BK=64 stages, prefetch 1 stage ahead --------------
// Tile 64x128, 256 thr = 4 waves 2x2, wave tile 32x64.
// A rows stride 2048; DUAL: k<1024 from A0, k>=1024 from A1 (FULL k index:
// h_b lives at columns [1024,2048) of A1's buffer). All loads plain cached.

template <int KTOT, bool DUAL>
__device__ __forceinline__ void kloop(const __bf16* __restrict__ A0,
                                      const __bf16* __restrict__ A1,
                                      const __bf16* __restrict__ W,
                                      int n0, int m0, int tid,
                                      __bf16* Alds, __bf16* Blds,
                                      f32x4 (&acc)[2][4]) {
    const int a_r = tid >> 2;             // 0..63
    const int a_c = (tid & 3) << 4;       // 0,16,32,48
    const int b_r = tid >> 1;             // 0..127
    const int b_c = (tid & 1) << 5;       // 0,32
    const __bf16* wrow  = W + (size_t)(n0 + b_r) * KTOT + b_c;
    const __bf16* arow0 = A0 + (m0 + a_r) * 2048 + a_c;
    const __bf16* arow1 = DUAL ? (A1 + (m0 + a_r) * 2048 + a_c) : arow0;

    const int l  = tid & 63, w = tid >> 6;
    const int wm = w & 1,   wn = w >> 1;
    const int lj = l & 15,  lq = l >> 4;

    #pragma unroll
    for (int i = 0; i < 2; ++i)
        #pragma unroll
        for (int j = 0; j < 4; ++j)
            acc[i][j] = (f32x4){0.f, 0.f, 0.f, 0.f};

    constexpr int NIT = KTOT / 64;

    uint4 ra0, ra1, rb0, rb1, rb2, rb3;
    auto lda = [&](int k0) {
        const __bf16* p = ((!DUAL || k0 < 1024) ? arow0 : arow1) + k0;
        ra0 = *(const uint4*)(p);
        ra1 = *(const uint4*)(p + 8);
    };
    auto ldb = [&](int k0) {
        const __bf16* p = wrow + k0;
        rb0 = *(const uint4*)(p);
        rb1 = *(const uint4*)(p + 8);
        rb2 = *(const uint4*)(p + 16);
        rb3 = *(const uint4*)(p + 24);
    };

    lda(0); ldb(0);

    const __bf16* Ap = Alds + (wm * 32 + lj) * LDSTR + lq * 8;
    const __bf16* Bp = Blds + (wn * 64 + lj) * LDSTR + lq * 8;

    for (int it = 0; it < NIT; ++it) {
        __syncthreads();
        *(uint4*)(Alds + a_r * LDSTR + a_c)      = ra0;
        *(uint4*)(Alds + a_r * LDSTR + a_c + 8)  = ra1;
        *(uint4*)(Blds + b_r * LDSTR + b_c)      = rb0;
        *(uint4*)(Blds + b_r * LDSTR + b_c + 8)  = rb1;
        *(uint4*)(Blds + b_r * LDSTR + b_c + 16) = rb2;
        *(uint4*)(Blds + b_r * LDSTR + b_c + 24) = rb3;
        __syncthreads();
        if (it + 1 < NIT) { int k0 = (it + 1) * 64; lda(k0); ldb(k0); }
        #pragma unroll
        for (int s = 0; s < 2; ++s) {
            bf16x8 af0 = *(const bf16x8*)(Ap + s * 32);
            bf16x8 af1 = *(const bf16x8*)(Ap + s * 32 + 16 * LDSTR);
            #pragma unroll
            for (int ni = 0; ni < 4; ++ni) {
                bf16x8 bfr = *(const bf16x8*)(Bp + s * 32 + ni * 16 * LDSTR);
                acc[0][ni] = __builtin_amdgcn_mfma_f32_16x16x32_bf16(af0, bfr, acc[0][ni], 0, 0, 0);
                acc[1][ni] = __builtin_amdgcn_mfma_f32_16x16x32_bf16(af1, bfr, acc[1][ni], 0, 0, 0);
            }
        }
    }
}

// ---------------- persistent LSTM kernel ------------------------------------
// 512 blocks, 2/CU. mb = XCD id (batch stripe of 64 rows); slot s in [0,64):
// s<32 -> L0-worker (gate-col block nb=s, layer-0 GEMM K=1024),
// s>=32 -> L1-worker (nb=s-32, layer-1 GEMM K=2048). L0 runs one timestep
// ahead of L1 (wavefront pipeline). All h traffic stays in the XCD's L2.

__global__ __launch_bounds__(256, 2)
void lstm_persist(const float* __restrict__ x,
                  const __bf16* __restrict__ W0p, const __bf16* __restrict__ W1p,
                  const __bf16* __restrict__ Wfcp,
                  const float* __restrict__ Wi0p, const float* __restrict__ b1p,
                  const float* __restrict__ bfc,
                  __bf16* __restrict__ Ab0, __bf16* __restrict__ Ab1,
                  char* __restrict__ cntpage, float* __restrict__ out) {
    __shared__ __attribute__((aligned(16))) __bf16 Alds[64 * LDSTR];
    __shared__ __attribute__((aligned(16))) __bf16 Blds[128 * LDSTR];
    __shared__ float Aux1[128];
    __shared__ float Xlds[64 * 9];
    __shared__ float Wxlds[128 * 9];
    __shared__ int role[2];

    const int tid = threadIdx.x;

    // ---- claim XCD-local role ----
    if (tid == 0) {
        int xcd = __builtin_amdgcn_s_getreg(63508) & 7;   // HW_REG_XCC_ID
        int* xcnt = (int*)(cntpage + 4096) + xcd;
        int slot = __hip_atomic_fetch_add(xcnt, 1, __ATOMIC_RELAXED,
                                          __HIP_MEMORY_SCOPE_AGENT);
        role[0] = xcd; role[1] = slot;
    }
    __syncthreads();
    const int mb = role[0];
    const int s  = role[1];
    const bool isL1 = (s >= 32);
    const int nb = isL1 ? (s - 32) : s;
    const int n0 = nb * 128, m0 = mb * 64;
    int* cA = (int*)(cntpage + (size_t)mb * 256);
    int* cB = (int*)(cntpage + (size_t)(8 + mb) * 256);

    // one-time per-block epilogue constants
    if (isL1) {
        if (tid < 128) Aux1[tid] = b1p[n0 + tid];
    } else {
        if (tid >= 128) {
            int nl = tid - 128;
            const float* sp = Wi0p + (n0 + nl) * 8;
            float* d = Wxlds + nl * 9;
            #pragma unroll
            for (int q = 0; q < 8; ++q) d[q] = sp[q];
        }
    }

    const int l  = tid & 63, w = tid >> 6;
    const int wm = w & 1,   wn = w >> 1;
    const int lj = l & 15,  lq = l >> 4;
    const int jc = (n0 >> 2) + wn * 16 + lj;   // this thread's hidden column

    float cst[2][4];
    #pragma unroll
    for (int i = 0; i < 2; ++i)
        #pragma unroll
        for (int r = 0; r < 4; ++r) cst[i][r] = 0.f;

    f32x4 acc[2][4];

    if (!isL1) {
        // ================= L0 worker: gates_a(t), t = 0..127 =================
        for (int t = 0; t < 128; ++t) {
            __bf16* hprev = (t & 1) ? Ab1 : Ab0;   // h(t-1); h(-1)=0 in Ab0
            __bf16* hcur  = (t & 1) ? Ab0 : Ab1;

            // stage x_t (read-only input, no dependency)
            if (tid < 64) {
                const float* xr = x + (m0 + tid) * 896 + t * 7;
                float* d = Xlds + tid * 9;
                #pragma unroll
                for (int q = 0; q < 7; ++q) d[q] = xr[q];
                d[7] = 1.0f;
            }

            // RAW: h_a(t-1) ready; WAR: L1 done reading h_a(t-2)
            if (tid == 0) { spin_ge(cA, 32 * t); spin_ge(cB, 32 * t - 32); }
            __syncthreads();
            inv_l1();
            kloop<1024, false>(hprev, nullptr, W0p, n0, m0, tid, Alds, Blds, acc);

            #pragma unroll
            for (int mi = 0; mi < 2; ++mi) {
                #pragma unroll
                for (int r = 0; r < 4; ++r) {
                    int ml = wm * 32 + mi * 16 + lq * 4 + r;
                    int m  = m0 + ml;
                    float pre[4];
                    #pragma unroll
                    for (int g = 0; g < 4; ++g) pre[g] = acc[mi][g][r];
                    const float* xr = Xlds + ml * 9;
                    #pragma unroll
                    for (int g = 0; g < 4; ++g) {
                        const float* wx = Wxlds + (wn * 64 + g * 16 + lj) * 9;
                        float sv = 0.f;
                        #pragma unroll
                        for (int q = 0; q < 8; ++q) sv += xr[q] * wx[q];
                        pre[g] += sv;
                    }
                    float ig = sigm_f(pre[0]);
                    float fg = sigm_f(pre[1]);
                    float gv = tanh_f(pre[2]);
                    float og = sigm_f(pre[3]);
                    float cn = fg * cst[mi][r] + ig * gv;
                    cst[mi][r] = cn;
                    hcur[m * 2048 + jc] = (__bf16)(og * tanh_f(cn));
                }
            }
            __syncthreads();             // barrier implies vmcnt(0) store drain
            if (tid == 0) signal_inc(cA);
        }
    } else {
        // ================= L1 worker: gates_b(t), t = 0..127 =================
        for (int t = 0; t < 128; ++t) {
            __bf16* hprev = (t & 1) ? Ab1 : Ab0;
            __bf16* hcur  = (t & 1) ? Ab0 : Ab1;

            // RAW: h_a(t) and h_b(t-1) ready; WAR on h_b(t-2) implied by cB
            if (tid == 0) { spin_ge(cA, 32 * (t + 1)); spin_ge(cB, 32 * t); }
            __syncthreads();
            inv_l1();
            kloop<2048, true>(hcur, hprev, W1p, n0, m0, tid, Alds, Blds, acc);

            #pragma unroll
            for (int mi = 0; mi < 2; ++mi) {
                #pragma unroll
                for (int r = 0; r < 4; ++r) {
                    int m = m0 + wm * 32 + mi * 16 + lq * 4 + r;
                    float pre[4];
                    #pragma unroll
                    for (int g = 0; g < 4; ++g)
                        pre[g] = acc[mi][g][r] + Aux1[wn * 64 + g * 16 + lj];
                    float ig = sigm_f(pre[0]);
                    float fg = sigm_f(pre[1]);
                    float gv = tanh_f(pre[2]);
                    float og = sigm_f(pre[3]);
                    float cn = fg * cst[mi][r] + ig * gv;
                    cst[mi][r] = cn;
                    hcur[m * 2048 + 1024 + jc] = (__bf16)(og * tanh_f(cn));
                }
            }
            __syncthreads();
            if (tid == 0) signal_inc(cB);
        }

        // ---- final FC: pred = h_b(127) @ Wfc^T + bfc  (L1 slots nb<6) ------
        if (nb < 6) {
            if (tid == 0) spin_ge(cB, 32 * 128);
            __syncthreads();
            inv_l1();
            if (tid < 128) {
                int n = n0 + tid;
                Aux1[tid] = (n < 672) ? bfc[n] : 0.f;
            }
            __syncthreads();
            // h_b(127) is in Ab0 (t=127 odd -> hcur=Ab0), cols 1024..2047
            kloop<1024, false>(Ab0 + 1024, nullptr, Wfcp, n0, m0, tid, Alds, Blds, acc);
            #pragma unroll
            for (int mi = 0; mi < 2; ++mi) {
                #pragma unroll
                for (int r = 0; r < 4; ++r) {
                    int m = m0 + wm * 32 + mi * 16 + lq * 4 + r;
                    #pragma unroll
                    for (int ni = 0; ni < 4; ++ni) {
                        int n = n0 + wn * 64 + ni * 16 + lj;
                        if (n < 672)
                            out[m * 672 + n] = acc[mi][ni][r] + Aux1[wn * 64 + ni * 16 + lj];
                    }
                }
            }
        }
    }
}

// ---------------- workspace layout (bytes) ----------------------------------
#define O_W0P   0u            // 4096*1024*2  = 8388608
#define O_W1P   8388608u      // 4096*2048*2  = 16777216
#define O_WFCP  25165824u     // 768*1024*2   = 1572864
#define O_WI0P  26738688u     // 4096*8*4     = 131072
#define O_B1P   26869760u     // 4096*4       = 16384
#define O_AB0   26886144u     // 512*2048*2   = 2097152   (zeroed: h(-1)=0)
#define O_CNT   28983296u     // 8192: 16 flags @256B + xcdCnt[8] @ +4096 (zeroed)
#define O_AB1   28991488u     // 512*2048*2   = 2097152
#define WS_NEED 31088640u

extern "C" void kernel_launch(void* const* d_in, const int* in_sizes, int n_in,
                              void* d_out, int out_size, void* d_ws, size_t ws_size,
                              hipStream_t stream) {
    const float* x   = (const float*)d_in[0];
    const float* Wi0 = (const float*)d_in[1];
    const float* Wh0 = (const float*)d_in[2];
    const float* b0  = (const float*)d_in[3];
    const float* Wi1 = (const float*)d_in[4];
    const float* Wh1 = (const float*)d_in[5];
    const float* b1  = (const float*)d_in[6];
    const float* Wfc = (const float*)d_in[7];
    const float* bfc = (const float*)d_in[8];
    float* out = (float*)d_out;
    char*  ws  = (char*)d_ws;
    if (ws_size < WS_NEED) return;

    __bf16* W0p  = (__bf16*)(ws + O_W0P);
    __bf16* W1p  = (__bf16*)(ws + O_W1P);
    __bf16* Wfcp = (__bf16*)(ws + O_WFCP);
    float*  Wi0p = (float*)(ws + O_WI0P);
    float*  b1p  = (float*)(ws + O_B1P);
    __bf16* Ab0  = (__bf16*)(ws + O_AB0);
    char*   cnt  = (char*)(ws + O_CNT);
    __bf16* Ab1  = (__bf16*)(ws + O_AB1);

    // zero h(-1) buffer + flag page (contiguous region)
    hipMemsetAsync(ws + O_AB0, 0, 2097152u + 8192u, stream);

    prep_w0   <<<4096, 256, 0, stream>>>(Wh0, W0p);
    prep_w1   <<<8192, 256, 0, stream>>>(Wi1, Wh1, W1p);
    prep_wfc  <<<768,  256, 0, stream>>>(Wfc, Wfcp);
    prep_small<<<16,   256, 0, stream>>>(Wi0, b0, b1, Wi0p, b1p);

    lstm_persist<<<512, 256, 0, stream>>>(x, W0p, W1p, Wfcp, Wi0p, b1p, bfc,
                                          Ab0, Ab1, cnt, out);
}